// Round 1
// baseline (1379.972 us; speedup 1.0000x reference)
//
#include <hip/hip_runtime.h>

#define H 128
#define MB 64          // edges (or nodes) per block
#define LDA 264        // LDS row stride (elems) for the [64 x 256] concat tile (+8 pad)
#define LDB 136        // LDS row stride for [64 x 128] tiles (+8 pad)

typedef __attribute__((ext_vector_type(8))) short bf16x8;
typedef __attribute__((ext_vector_type(4))) short s16x4;
typedef __attribute__((ext_vector_type(4))) float f32x4;

__device__ __forceinline__ short f2bf(float f) {
    union { float f; unsigned u; } v; v.f = f;
    unsigned r = v.u + 0x7FFF + ((v.u >> 16) & 1);   // RTNE
    return (short)(r >> 16);
}
__device__ __forceinline__ float bf2f(short s) {
    union { unsigned u; float f; } v;
    v.u = ((unsigned)(unsigned short)s) << 16;
    return v.f;
}

// ---------------- weight prep: fp32 [K,N] -> bf16 transposed [N,K] ----------------
__global__ __launch_bounds__(256) void prep_weights(
    const float* __restrict__ W1, const float* __restrict__ W2,
    const float* __restrict__ WL,
    short* __restrict__ W1T, short* __restrict__ W2T, short* __restrict__ WLT)
{
    int tid = blockIdx.x * 256 + threadIdx.x;      // 0..32767
    {   // W1: [256,128] -> W1T [128][256]
        int n = tid >> 8, k = tid & 255;
        W1T[n * 256 + k] = f2bf(W1[k * 128 + n]);
    }
    if (tid < 16384) {  // W2, W_lift: [128,128] -> [128][128]
        int n = tid >> 7, k = tid & 127;
        W2T[n * 128 + k] = f2bf(W2[k * 128 + n]);
        WLT[n * 128 + k] = f2bf(WL[k * 128 + n]);
    }
}

// ---------------- CSR build ----------------
__global__ __launch_bounds__(256) void count_deg(
    const int* __restrict__ eidx, int* __restrict__ deg, int twoE)
{
    int t = blockIdx.x * 256 + threadIdx.x;
    if (t < twoE) atomicAdd(&deg[eidx[t]], 1);
}

// single-block exclusive scan of deg[N] -> row_start[N+1] and cursor[N]
__global__ __launch_bounds__(1024) void scan_deg(
    const int* __restrict__ deg, int* __restrict__ row_start,
    int* __restrict__ cursor, int N)
{
    __shared__ int part[1024];
    const int t = threadIdx.x;
    const int chunk = (N + 1023) >> 10;
    const int b = t * chunk;
    const int e = (b + chunk < N) ? (b + chunk) : N;
    int s = 0;
    for (int j = b; j < e; ++j) s += deg[j];
    part[t] = s;
    __syncthreads();
    for (int off = 1; off < 1024; off <<= 1) {
        int v = part[t];
        int u = (t >= off) ? part[t - off] : 0;
        __syncthreads();
        part[t] = v + u;
        __syncthreads();
    }
    int run = (t == 0) ? 0 : part[t - 1];
    for (int j = b; j < e; ++j) {
        int d = deg[j];
        row_start[j] = run;
        cursor[j]    = run;
        run += d;
    }
    if (t == 1023) row_start[N] = part[1023];
}

__global__ __launch_bounds__(256) void fill_csr(
    const int* __restrict__ eidx, int* __restrict__ cursor,
    int* __restrict__ csr, int E)
{
    int t = blockIdx.x * 256 + threadIdx.x;
    if (t < 2 * E) {
        int node = eidx[t];
        int e = (t < E) ? t : (t - E);
        int pos = atomicAdd(&cursor[node], 1);
        csr[pos] = e;
    }
}

// ---------------- PATH A: fused edge kernel, h stored bf16 in workspace -------
// per block: 64 edges. GEMM1: [64,256]x[256,128] -> h; store h bf16; GEMM2 in place.
__global__ __launch_bounds__(256) void edge_fused(
    const float* __restrict__ node_rep, const float* __restrict__ edge_rep,
    const int* __restrict__ eidx,
    const short* __restrict__ W1T, const short* __restrict__ WLT,
    const float* __restrict__ eps2p,
    short* __restrict__ hbuf, float* __restrict__ edge_out, int E)
{
    __shared__ short sA[MB * LDA];   // concat(lift, edge_rep) bf16; lift half becomes b2

    const int tid = threadIdx.x;
    const int e0  = blockIdx.x * MB;
    const float e2 = 1.f + eps2p[0];

    // ---- stage: 4 threads per edge row, each covers 32 cols ----
    {
        int row  = tid >> 2;
        int cseg = (tid & 3) << 5;        // 0,32,64,96
        int e = e0 + row;
        short* rowA = sA + row * LDA;
        if (e < E) {
            int sIdx = eidx[e], dIdx = eidx[E + e];
            const float4* sp = (const float4*)(node_rep + (size_t)sIdx * H + cseg);
            const float4* dp = (const float4*)(node_rep + (size_t)dIdx * H + cseg);
            const float4* ep = (const float4*)(edge_rep + (size_t)e * H + cseg);
            #pragma unroll
            for (int j = 0; j < 8; ++j) {
                float4 a = sp[j], b = dp[j], c = ep[j];
                int cc = cseg + 4 * j;
                s16x4 lift = { f2bf(a.x + b.x), f2bf(a.y + b.y),
                               f2bf(a.z + b.z), f2bf(a.w + b.w) };
                s16x4 er   = { f2bf(c.x), f2bf(c.y), f2bf(c.z), f2bf(c.w) };
                *(s16x4*)&rowA[cc]      = lift;
                *(s16x4*)&rowA[H + cc]  = er;
            }
        } else {
            s16x4 z = {0, 0, 0, 0};
            #pragma unroll
            for (int j = 0; j < 8; ++j) {
                int cc = cseg + 4 * j;
                *(s16x4*)&rowA[cc]     = z;
                *(s16x4*)&rowA[H + cc] = z;
            }
        }
    }
    __syncthreads();

    const int wave = tid >> 6;
    const int lane = tid & 63;
    const int m = lane & 15;     // A row / B col / D col
    const int q = lane >> 4;     // k-quad, D row group

    // ---- GEMM1 ----
    f32x4 zero = {0.f, 0.f, 0.f, 0.f};
    f32x4 acc[4][2];
    #pragma unroll
    for (int mt = 0; mt < 4; ++mt)
        #pragma unroll
        for (int nt = 0; nt < 2; ++nt) acc[mt][nt] = zero;

    #pragma unroll
    for (int ks = 0; ks < 8; ++ks) {
        int k0 = ks * 32 + q * 8;
        bf16x8 aF[4];
        #pragma unroll
        for (int mt = 0; mt < 4; ++mt)
            aF[mt] = *(const bf16x8*)&sA[(mt * 16 + m) * LDA + k0];
        bf16x8 bF[2];
        #pragma unroll
        for (int nt = 0; nt < 2; ++nt) {
            int n = (wave << 5) + (nt << 4) + m;
            bF[nt] = *(const bf16x8*)&W1T[n * 256 + k0];
        }
        #pragma unroll
        for (int mt = 0; mt < 4; ++mt)
            #pragma unroll
            for (int nt = 0; nt < 2; ++nt)
                acc[mt][nt] = __builtin_amdgcn_mfma_f32_16x16x32_bf16(
                    aF[mt], bF[nt], acc[mt][nt], 0, 0, 0);
    }
    __syncthreads();   // all waves done reading sA before in-place update

    // ---- epilogue 1: relu, store h bf16, b2 = e2*h + lift in place in sA ----
    #pragma unroll
    for (int mt = 0; mt < 4; ++mt) {
        #pragma unroll
        for (int nt = 0; nt < 2; ++nt) {
            int col = (wave << 5) + (nt << 4) + m;
            #pragma unroll
            for (int i = 0; i < 4; ++i) {
                int rr = (mt << 4) + (q << 2) + i;
                if (e0 + rr < E) {
                    float h = acc[mt][nt][i];
                    h = h > 0.f ? h : 0.f;
                    hbuf[(size_t)(e0 + rr) * H + col] = f2bf(h);
                    float b2 = e2 * h + bf2f(sA[rr * LDA + col]);
                    sA[rr * LDA + col] = f2bf(b2);
                }
            }
        }
    }
    __syncthreads();

    // ---- GEMM2: edge_out = relu(B2 @ W_lift), B2 = first 128 cols of sA ----
    f32x4 acc2[4][2];
    #pragma unroll
    for (int mt = 0; mt < 4; ++mt)
        #pragma unroll
        for (int nt = 0; nt < 2; ++nt) acc2[mt][nt] = zero;

    #pragma unroll
    for (int ks = 0; ks < 4; ++ks) {
        int k0 = ks * 32 + q * 8;
        bf16x8 aF[4];
        #pragma unroll
        for (int mt = 0; mt < 4; ++mt)
            aF[mt] = *(const bf16x8*)&sA[(mt * 16 + m) * LDA + k0];
        bf16x8 bF[2];
        #pragma unroll
        for (int nt = 0; nt < 2; ++nt) {
            int n = (wave << 5) + (nt << 4) + m;
            bF[nt] = *(const bf16x8*)&WLT[n * 128 + k0];
        }
        #pragma unroll
        for (int mt = 0; mt < 4; ++mt)
            #pragma unroll
            for (int nt = 0; nt < 2; ++nt)
                acc2[mt][nt] = __builtin_amdgcn_mfma_f32_16x16x32_bf16(
                    aF[mt], bF[nt], acc2[mt][nt], 0, 0, 0);
    }

    #pragma unroll
    for (int mt = 0; mt < 4; ++mt) {
        #pragma unroll
        for (int nt = 0; nt < 2; ++nt) {
            int col = (wave << 5) + (nt << 4) + m;
            #pragma unroll
            for (int i = 0; i < 4; ++i) {
                int rr = (mt << 4) + (q << 2) + i;
                if (e0 + rr < E) {
                    float v = acc2[mt][nt][i];
                    edge_out[(size_t)(e0 + rr) * H + col] = v > 0.f ? v : 0.f;
                }
            }
        }
    }
}

// ---------------- PATH B: split edge kernels, h transits f32 via edge_out ----
__global__ __launch_bounds__(256) void edge_h_kernel(
    const float* __restrict__ node_rep, const float* __restrict__ edge_rep,
    const int* __restrict__ eidx, const short* __restrict__ W1T,
    float* __restrict__ hbuf, int E)
{
    __shared__ short sA[MB * LDA];
    const int tid = threadIdx.x;
    const int e0  = blockIdx.x * MB;
    {
        int row  = tid >> 2;
        int cseg = (tid & 3) << 5;
        int e = e0 + row;
        short* rowA = sA + row * LDA;
        if (e < E) {
            int sIdx = eidx[e], dIdx = eidx[E + e];
            const float4* sp = (const float4*)(node_rep + (size_t)sIdx * H + cseg);
            const float4* dp = (const float4*)(node_rep + (size_t)dIdx * H + cseg);
            const float4* ep = (const float4*)(edge_rep + (size_t)e * H + cseg);
            #pragma unroll
            for (int j = 0; j < 8; ++j) {
                float4 a = sp[j], b = dp[j], c = ep[j];
                int cc = cseg + 4 * j;
                s16x4 lift = { f2bf(a.x + b.x), f2bf(a.y + b.y),
                               f2bf(a.z + b.z), f2bf(a.w + b.w) };
                s16x4 er   = { f2bf(c.x), f2bf(c.y), f2bf(c.z), f2bf(c.w) };
                *(s16x4*)&rowA[cc]      = lift;
                *(s16x4*)&rowA[H + cc]  = er;
            }
        } else {
            s16x4 z = {0, 0, 0, 0};
            #pragma unroll
            for (int j = 0; j < 8; ++j) {
                int cc = cseg + 4 * j;
                *(s16x4*)&rowA[cc]     = z;
                *(s16x4*)&rowA[H + cc] = z;
            }
        }
    }
    __syncthreads();

    const int wave = tid >> 6;
    const int lane = tid & 63;
    const int m = lane & 15;
    const int q = lane >> 4;

    f32x4 zero = {0.f, 0.f, 0.f, 0.f};
    f32x4 acc[4][2];
    #pragma unroll
    for (int mt = 0; mt < 4; ++mt)
        #pragma unroll
        for (int nt = 0; nt < 2; ++nt) acc[mt][nt] = zero;

    #pragma unroll
    for (int ks = 0; ks < 8; ++ks) {
        int k0 = ks * 32 + q * 8;
        bf16x8 aF[4];
        #pragma unroll
        for (int mt = 0; mt < 4; ++mt)
            aF[mt] = *(const bf16x8*)&sA[(mt * 16 + m) * LDA + k0];
        bf16x8 bF[2];
        #pragma unroll
        for (int nt = 0; nt < 2; ++nt) {
            int n = (wave << 5) + (nt << 4) + m;
            bF[nt] = *(const bf16x8*)&W1T[n * 256 + k0];
        }
        #pragma unroll
        for (int mt = 0; mt < 4; ++mt)
            #pragma unroll
            for (int nt = 0; nt < 2; ++nt)
                acc[mt][nt] = __builtin_amdgcn_mfma_f32_16x16x32_bf16(
                    aF[mt], bF[nt], acc[mt][nt], 0, 0, 0);
    }

    #pragma unroll
    for (int mt = 0; mt < 4; ++mt) {
        #pragma unroll
        for (int nt = 0; nt < 2; ++nt) {
            int col = (wave << 5) + (nt << 4) + m;
            #pragma unroll
            for (int i = 0; i < 4; ++i) {
                int rr = (mt << 4) + (q << 2) + i;
                if (e0 + rr < E) {
                    float h = acc[mt][nt][i];
                    hbuf[(size_t)(e0 + rr) * H + col] = h > 0.f ? h : 0.f;
                }
            }
        }
    }
}

// finalize: edge_out = relu((e2*h + lift) @ W_lift); h f32 read from eo, written in place
__global__ __launch_bounds__(256) void edge_finalize(
    const float* __restrict__ node_rep, const int* __restrict__ eidx,
    const short* __restrict__ WLT, const float* __restrict__ eps2p,
    float* __restrict__ eo, int E)
{
    __shared__ short sB[MB * LDB];
    const int tid = threadIdx.x;
    const int e0  = blockIdx.x * MB;
    const float e2 = 1.f + eps2p[0];
    {
        int row  = tid >> 2;
        int cseg = (tid & 3) << 5;
        int e = e0 + row;
        short* rowB = sB + row * LDB;
        if (e < E) {
            int sIdx = eidx[e], dIdx = eidx[E + e];
            const float4* hp = (const float4*)(eo + (size_t)e * H + cseg);
            const float4* sp = (const float4*)(node_rep + (size_t)sIdx * H + cseg);
            const float4* dp = (const float4*)(node_rep + (size_t)dIdx * H + cseg);
            #pragma unroll
            for (int j = 0; j < 8; ++j) {
                float4 hv = hp[j], a = sp[j], b = dp[j];
                int cc = cseg + 4 * j;
                s16x4 v = { f2bf(e2 * hv.x + a.x + b.x), f2bf(e2 * hv.y + a.y + b.y),
                            f2bf(e2 * hv.z + a.z + b.z), f2bf(e2 * hv.w + a.w + b.w) };
                *(s16x4*)&rowB[cc] = v;
            }
        } else {
            s16x4 z = {0, 0, 0, 0};
            #pragma unroll
            for (int j = 0; j < 8; ++j) *(s16x4*)&rowB[cseg + 4 * j] = z;
        }
    }
    __syncthreads();

    const int wave = tid >> 6;
    const int lane = tid & 63;
    const int m = lane & 15;
    const int q = lane >> 4;

    f32x4 zero = {0.f, 0.f, 0.f, 0.f};
    f32x4 acc2[4][2];
    #pragma unroll
    for (int mt = 0; mt < 4; ++mt)
        #pragma unroll
        for (int nt = 0; nt < 2; ++nt) acc2[mt][nt] = zero;

    #pragma unroll
    for (int ks = 0; ks < 4; ++ks) {
        int k0 = ks * 32 + q * 8;
        bf16x8 aF[4];
        #pragma unroll
        for (int mt = 0; mt < 4; ++mt)
            aF[mt] = *(const bf16x8*)&sB[(mt * 16 + m) * LDB + k0];
        bf16x8 bF[2];
        #pragma unroll
        for (int nt = 0; nt < 2; ++nt) {
            int n = (wave << 5) + (nt << 4) + m;
            bF[nt] = *(const bf16x8*)&WLT[n * 128 + k0];
        }
        #pragma unroll
        for (int mt = 0; mt < 4; ++mt)
            #pragma unroll
            for (int nt = 0; nt < 2; ++nt)
                acc2[mt][nt] = __builtin_amdgcn_mfma_f32_16x16x32_bf16(
                    aF[mt], bF[nt], acc2[mt][nt], 0, 0, 0);
    }

    #pragma unroll
    for (int mt = 0; mt < 4; ++mt) {
        #pragma unroll
        for (int nt = 0; nt < 2; ++nt) {
            int col = (wave << 5) + (nt << 4) + m;
            #pragma unroll
            for (int i = 0; i < 4; ++i) {
                int rr = (mt << 4) + (q << 2) + i;
                if (e0 + rr < E) {
                    float v = acc2[mt][nt][i];
                    eo[(size_t)(e0 + rr) * H + col] = v > 0.f ? v : 0.f;
                }
            }
        }
    }
}

// ---------------- node aggregation: lvl[n] = sum of h over incident edges ----
// one wave per node, lane owns 2 columns
__global__ __launch_bounds__(256) void node_aggr_bf16(
    const unsigned* __restrict__ hbuf32, const int* __restrict__ csr,
    const int* __restrict__ row_start, float* __restrict__ lvl, int N)
{
    const int wid = threadIdx.x >> 6, lane = threadIdx.x & 63;
    const int n = blockIdx.x * 4 + wid;
    if (n >= N) return;
    const int beg = row_start[n], end = row_start[n + 1];
    float a0 = 0.f, a1 = 0.f;
    int i = beg;
    for (; i + 4 <= end; i += 4) {
        int e0 = csr[i], e1 = csr[i + 1], e2 = csr[i + 2], e3 = csr[i + 3];
        unsigned v0 = hbuf32[(size_t)e0 * 64 + lane];
        unsigned v1 = hbuf32[(size_t)e1 * 64 + lane];
        unsigned v2 = hbuf32[(size_t)e2 * 64 + lane];
        unsigned v3 = hbuf32[(size_t)e3 * 64 + lane];
        a0 += (bf2f((short)(v0 & 0xffff)) + bf2f((short)(v1 & 0xffff)))
            + (bf2f((short)(v2 & 0xffff)) + bf2f((short)(v3 & 0xffff)));
        a1 += (bf2f((short)(v0 >> 16)) + bf2f((short)(v1 >> 16)))
            + (bf2f((short)(v2 >> 16)) + bf2f((short)(v3 >> 16)));
    }
    for (; i < end; ++i) {
        int e = csr[i];
        unsigned v = hbuf32[(size_t)e * 64 + lane];
        a0 += bf2f((short)(v & 0xffff));
        a1 += bf2f((short)(v >> 16));
    }
    float2 out; out.x = a0; out.y = a1;
    *(float2*)(lvl + (size_t)n * H + 2 * lane) = out;
}

__global__ __launch_bounds__(256) void node_aggr_f32(
    const float* __restrict__ hbuf, const int* __restrict__ csr,
    const int* __restrict__ row_start, float* __restrict__ lvl, int N)
{
    const int wid = threadIdx.x >> 6, lane = threadIdx.x & 63;
    const int n = blockIdx.x * 4 + wid;
    if (n >= N) return;
    const int beg = row_start[n], end = row_start[n + 1];
    float a0 = 0.f, a1 = 0.f;
    int i = beg;
    for (; i + 4 <= end; i += 4) {
        int e0 = csr[i], e1 = csr[i + 1], e2 = csr[i + 2], e3 = csr[i + 3];
        float2 v0 = *(const float2*)(hbuf + (size_t)e0 * H + 2 * lane);
        float2 v1 = *(const float2*)(hbuf + (size_t)e1 * H + 2 * lane);
        float2 v2 = *(const float2*)(hbuf + (size_t)e2 * H + 2 * lane);
        float2 v3 = *(const float2*)(hbuf + (size_t)e3 * H + 2 * lane);
        a0 += (v0.x + v1.x) + (v2.x + v3.x);
        a1 += (v0.y + v1.y) + (v2.y + v3.y);
    }
    for (; i < end; ++i) {
        int e = csr[i];
        float2 v = *(const float2*)(hbuf + (size_t)e * H + 2 * lane);
        a0 += v.x; a1 += v.y;
    }
    float2 out; out.x = a0; out.y = a1;
    *(float2*)(lvl + (size_t)n * H + 2 * lane) = out;
}

// ---------------- LEGACY edge kernel (atomic scatter) -- tiny-ws fallback ----
__global__ __launch_bounds__(256) void edge_kernel(
    const float* __restrict__ node_rep, const float* __restrict__ edge_rep,
    const int* __restrict__ eidx,
    const short* __restrict__ W1T, const short* __restrict__ WLT,
    const float* __restrict__ eps2p,
    float* __restrict__ lvl, float* __restrict__ edge_out, int E)
{
    __shared__ short sA[MB * LDA];
    __shared__ short sB[MB * LDB];
    __shared__ int sSrc[MB], sDst[MB];

    const int tid = threadIdx.x;
    const int e0  = blockIdx.x * MB;
    const float e2 = 1.f + eps2p[0];
    {
        int row  = tid >> 2;
        int cseg = (tid & 3) << 5;
        int e = e0 + row;
        int sIdx = 0, dIdx = 0;
        bool ev = (e < E);
        if (ev) { sIdx = eidx[e]; dIdx = eidx[E + e]; }
        if ((tid & 3) == 0) { sSrc[row] = sIdx; sDst[row] = dIdx; }
        short* rowA = sA + row * LDA;
        if (ev) {
            const float4* sp = (const float4*)(node_rep + (size_t)sIdx * H + cseg);
            const float4* dp = (const float4*)(node_rep + (size_t)dIdx * H + cseg);
            const float4* ep = (const float4*)(edge_rep + (size_t)e * H + cseg);
            #pragma unroll
            for (int j = 0; j < 8; ++j) {
                float4 a = sp[j], b = dp[j], c = ep[j];
                int cc = cseg + 4 * j;
                s16x4 lift = { f2bf(a.x + b.x), f2bf(a.y + b.y),
                               f2bf(a.z + b.z), f2bf(a.w + b.w) };
                s16x4 er   = { f2bf(c.x), f2bf(c.y), f2bf(c.z), f2bf(c.w) };
                *(s16x4*)&rowA[cc]      = lift;
                *(s16x4*)&rowA[H + cc]  = er;
            }
        } else {
            s16x4 z = {0, 0, 0, 0};
            #pragma unroll
            for (int j = 0; j < 8; ++j) {
                int cc = cseg + 4 * j;
                *(s16x4*)&rowA[cc]     = z;
                *(s16x4*)&rowA[H + cc] = z;
            }
        }
    }
    __syncthreads();

    const int wave = tid >> 6;
    const int lane = tid & 63;
    const int m = lane & 15;
    const int q = lane >> 4;

    f32x4 zero = {0.f, 0.f, 0.f, 0.f};
    f32x4 acc[4][2];
    #pragma unroll
    for (int mt = 0; mt < 4; ++mt)
        #pragma unroll
        for (int nt = 0; nt < 2; ++nt) acc[mt][nt] = zero;

    #pragma unroll
    for (int ks = 0; ks < 8; ++ks) {
        int k0 = ks * 32 + q * 8;
        bf16x8 aF[4];
        #pragma unroll
        for (int mt = 0; mt < 4; ++mt)
            aF[mt] = *(const bf16x8*)&sA[(mt * 16 + m) * LDA + k0];
        bf16x8 bF[2];
        #pragma unroll
        for (int nt = 0; nt < 2; ++nt) {
            int n = (wave << 5) + (nt << 4) + m;
            bF[nt] = *(const bf16x8*)&W1T[n * 256 + k0];
        }
        #pragma unroll
        for (int mt = 0; mt < 4; ++mt)
            #pragma unroll
            for (int nt = 0; nt < 2; ++nt)
                acc[mt][nt] = __builtin_amdgcn_mfma_f32_16x16x32_bf16(
                    aF[mt], bF[nt], acc[mt][nt], 0, 0, 0);
    }

    #pragma unroll
    for (int mt = 0; mt < 4; ++mt) {
        #pragma unroll
        for (int nt = 0; nt < 2; ++nt) {
            int col = (wave << 5) + (nt << 4) + m;
            #pragma unroll
            for (int i = 0; i < 4; ++i) {
                int rr = (mt << 4) + (q << 2) + i;
                if (e0 + rr < E) {
                    float h = acc[mt][nt][i];
                    h = h > 0.f ? h : 0.f;
                    int sn = sSrc[rr], dn = sDst[rr];
                    atomicAdd(lvl + (size_t)sn * H + col, h);
                    atomicAdd(lvl + (size_t)dn * H + col, h);
                    float b2 = e2 * h + bf2f(sA[rr * LDA + col]);
                    sB[rr * LDB + col] = f2bf(b2);
                }
            }
        }
    }
    __syncthreads();

    f32x4 acc2[4][2];
    #pragma unroll
    for (int mt = 0; mt < 4; ++mt)
        #pragma unroll
        for (int nt = 0; nt < 2; ++nt) acc2[mt][nt] = zero;

    #pragma unroll
    for (int ks = 0; ks < 4; ++ks) {
        int k0 = ks * 32 + q * 8;
        bf16x8 aF[4];
        #pragma unroll
        for (int mt = 0; mt < 4; ++mt)
            aF[mt] = *(const bf16x8*)&sB[(mt * 16 + m) * LDB + k0];
        bf16x8 bF[2];
        #pragma unroll
        for (int nt = 0; nt < 2; ++nt) {
            int n = (wave << 5) + (nt << 4) + m;
            bF[nt] = *(const bf16x8*)&WLT[n * 128 + k0];
        }
        #pragma unroll
        for (int mt = 0; mt < 4; ++mt)
            #pragma unroll
            for (int nt = 0; nt < 2; ++nt)
                acc2[mt][nt] = __builtin_amdgcn_mfma_f32_16x16x32_bf16(
                    aF[mt], bF[nt], acc2[mt][nt], 0, 0, 0);
    }

    #pragma unroll
    for (int mt = 0; mt < 4; ++mt) {
        #pragma unroll
        for (int nt = 0; nt < 2; ++nt) {
            int col = (wave << 5) + (nt << 4) + m;
            #pragma unroll
            for (int i = 0; i < 4; ++i) {
                int rr = (mt << 4) + (q << 2) + i;
                if (e0 + rr < E) {
                    float v = acc2[mt][nt][i];
                    edge_out[(size_t)(e0 + rr) * H + col] = v > 0.f ? v : 0.f;
                }
            }
        }
    }
}

// ---------------- node kernel ----------------
// node_out = relu(((1+eps1)*node_rep + lvl) @ W2); lvl may alias node_out.
__global__ __launch_bounds__(256) void node_kernel(
    const float* __restrict__ node_rep, const float* __restrict__ lvl,
    const short* __restrict__ W2T, const float* __restrict__ eps1p,
    float* __restrict__ node_out, int N)
{
    __shared__ short sA[MB * LDB];

    const int tid = threadIdx.x;
    const int r0  = blockIdx.x * MB;
    const float e1 = 1.f + eps1p[0];

    {
        int row  = tid >> 2;
        int cseg = (tid & 3) << 5;
        int r = r0 + row;
        short* rowA = sA + row * LDB;
        if (r < N) {
            const float4* np = (const float4*)(node_rep + (size_t)r * H + cseg);
            const float4* lp = (const float4*)(lvl + (size_t)r * H + cseg);
            #pragma unroll
            for (int j = 0; j < 8; ++j) {
                float4 a = np[j], b = lp[j];
                int cc = cseg + 4 * j;
                s16x4 v = { f2bf(e1 * a.x + b.x), f2bf(e1 * a.y + b.y),
                            f2bf(e1 * a.z + b.z), f2bf(e1 * a.w + b.w) };
                *(s16x4*)&rowA[cc] = v;
            }
        } else {
            s16x4 z = {0, 0, 0, 0};
            #pragma unroll
            for (int j = 0; j < 8; ++j) *(s16x4*)&rowA[cseg + 4 * j] = z;
        }
    }
    __syncthreads();

    const int wave = tid >> 6;
    const int lane = tid & 63;
    const int m = lane & 15;
    const int q = lane >> 4;

    f32x4 zero = {0.f, 0.f, 0.f, 0.f};
    f32x4 acc[4][2];
    #pragma unroll
    for (int mt = 0; mt < 4; ++mt)
        #pragma unroll
        for (int nt = 0; nt < 2; ++nt) acc[mt][nt] = zero;

    #pragma unroll
    for (int ks = 0; ks < 4; ++ks) {
        int k0 = ks * 32 + q * 8;
        bf16x8 aF[4];
        #pragma unroll
        for (int mt = 0; mt < 4; ++mt)
            aF[mt] = *(const bf16x8*)&sA[(mt * 16 + m) * LDB + k0];
        bf16x8 bF[2];
        #pragma unroll
        for (int nt = 0; nt < 2; ++nt) {
            int n = (wave << 5) + (nt << 4) + m;
            bF[nt] = *(const bf16x8*)&W2T[n * 128 + k0];
        }
        #pragma unroll
        for (int mt = 0; mt < 4; ++mt)
            #pragma unroll
            for (int nt = 0; nt < 2; ++nt)
                acc[mt][nt] = __builtin_amdgcn_mfma_f32_16x16x32_bf16(
                    aF[mt], bF[nt], acc[mt][nt], 0, 0, 0);
    }

    #pragma unroll
    for (int mt = 0; mt < 4; ++mt) {
        #pragma unroll
        for (int nt = 0; nt < 2; ++nt) {
            int col = (wave << 5) + (nt << 4) + m;
            #pragma unroll
            for (int i = 0; i < 4; ++i) {
                int rr = (mt << 4) + (q << 2) + i;
                if (r0 + rr < N) {
                    float v = acc[mt][nt][i];
                    node_out[(size_t)(r0 + rr) * H + col] = v > 0.f ? v : 0.f;
                }
            }
        }
    }
}

static inline size_t algn(size_t x) { return (x + 255) & ~(size_t)255; }

extern "C" void kernel_launch(void* const* d_in, const int* in_sizes, int n_in,
                              void* d_out, int out_size, void* d_ws, size_t ws_size,
                              hipStream_t stream) {
    const float* node_rep = (const float*)d_in[0];
    const float* edge_rep = (const float*)d_in[1];
    const int*   eidx     = (const int*)d_in[2];
    const float* W1       = (const float*)d_in[3];
    const float* W2       = (const float*)d_in[4];
    const float* WL       = (const float*)d_in[5];
    const float* eps1     = (const float*)d_in[6];
    const float* eps2     = (const float*)d_in[7];

    const int N = in_sizes[0] / H;     // 50000
    const int E = in_sizes[1] / H;     // 800000

    float* node_out = (float*)d_out;
    float* edge_out = (float*)d_out + (size_t)N * H;
    float* lvl = node_out;             // lvl aliases node_out (node_kernel is in-place safe)

    char* ws = (char*)d_ws;
    short* W1T = (short*)ws;                       // 64 KB
    short* W2T = (short*)(ws + 65536);             // 32 KB
    short* WLT = (short*)(ws + 65536 + 32768);     // 32 KB
    size_t off = 131072;

    int* deg       = (int*)(ws + off); off += algn((size_t)N * 4);
    int* row_start = (int*)(ws + off); off += algn((size_t)(N + 1) * 4);
    int* cursor    = (int*)(ws + off); off += algn((size_t)N * 4);
    int* csr       = (int*)(ws + off); off += algn((size_t)2 * E * 4);
    const size_t need_small = off;
    short* hbuf    = (short*)(ws + off);
    const size_t need_big = off + algn((size_t)E * H * sizeof(short));

    prep_weights<<<128, 256, 0, stream>>>(W1, W2, WL, W1T, W2T, WLT);

    const int twoE = 2 * E;
    const int egrid = (E + MB - 1) / MB;
    const int ngrid = (N + MB - 1) / MB;

    if (ws_size >= need_small) {
        // build CSR incidence lists (int atomics only: 2E ops)
        hipMemsetAsync(deg, 0, (size_t)N * 4, stream);
        count_deg<<<(twoE + 255) / 256, 256, 0, stream>>>(eidx, deg, twoE);
        scan_deg<<<1, 1024, 0, stream>>>(deg, row_start, cursor, N);
        fill_csr<<<(twoE + 255) / 256, 256, 0, stream>>>(eidx, cursor, csr, E);

        if (ws_size >= need_big) {
            // PATH A: fused edge kernel, h bf16 in workspace
            edge_fused<<<egrid, 256, 0, stream>>>(
                node_rep, edge_rep, eidx, W1T, WLT, eps2, hbuf, edge_out, E);
            node_aggr_bf16<<<(N + 3) / 4, 256, 0, stream>>>(
                (const unsigned*)hbuf, csr, row_start, lvl, N);
            node_kernel<<<ngrid, 256, 0, stream>>>(
                node_rep, lvl, W2T, eps1, node_out, N);
        } else {
            // PATH B: h f32 transits through edge_out region
            edge_h_kernel<<<egrid, 256, 0, stream>>>(
                node_rep, edge_rep, eidx, W1T, edge_out, E);
            node_aggr_f32<<<(N + 3) / 4, 256, 0, stream>>>(
                edge_out, csr, row_start, lvl, N);
            node_kernel<<<ngrid, 256, 0, stream>>>(
                node_rep, lvl, W2T, eps1, node_out, N);
            edge_finalize<<<egrid, 256, 0, stream>>>(
                node_rep, eidx, WLT, eps2, edge_out, E);
        }
    } else {
        // LEGACY: atomic scatter
        hipMemsetAsync(lvl, 0, (size_t)N * H * sizeof(float), stream);
        edge_kernel<<<egrid, 256, 0, stream>>>(
            node_rep, edge_rep, eidx, W1T, WLT, eps2, lvl, edge_out, E);
        node_kernel<<<ngrid, 256, 0, stream>>>(
            node_rep, lvl, W2T, eps1, node_out, N);
    }
}